// Round 7
// baseline (867.648 us; speedup 1.0000x reference)
//
#include <hip/hip_runtime.h>

// Block-diagonal linear + bias + ReLU on MI355X (gfx950), fp32.
// out[b,p,o] = relu(sum_k x[b,p,k] * W[p,k,o] + bias[p,o])
// B=16384, P=64, K=64, O=64.
//
// R5 lesson (measured): x-from-LDS is pinned at 4 FMA per ds_read_b128
// (per-lane x reuse = 1), i.e. ~216 LDS-cyc vs 128 VALU-cyc per k4 per
// wave, and the single per-CU LDS pipe serves 4 SIMDs -> LDS-issue-bound
// at 222us (VALUBusy 78% = interleave, not useful work).
// R6 structure: x comes off the LDS pipe entirely. All 64 lanes need the
// SAME x quad (lane = output channel o), so x is read as a broadcast
// global_load_dwordx4 (64 identical addrs -> one 16B L1 transaction,
// TA pipe). LDS keeps only W[p] (4 ds_read_b32 per k4, 2-way bank alias
// = free, 0 conflicts measured in R5). Row base addresses are hoisted
// per-slab; k4 advances via the 13-bit immediate offset (16*k4 <= 240B).
// acc[r] accumulates k strictly in order -> bit-exact vs reference
// (R5 absmax = 0.0).
//
// Floors: FMA 55us (157 TF fp32 vector), HBM ~85-100us. Expect 100-140us.
// (R6 bench was an infra GPUAcquisitionTimeout — identical kernel
// resubmitted for measurement.)

#define KDIM   64
#define ODIM   64
#define PK     4096              // P*K = row stride of x / out in floats
#define SLABROWS 16              // rows per wave per slab
#define NSLABS 4
#define ROWS_PER_BLOCK 256       // 4 waves * 16 rows * 4 slabs
#define NBLOCKGROUPS (16384 / ROWS_PER_BLOCK)  // 64

typedef __attribute__((address_space(1))) const unsigned int gl_u32;
typedef __attribute__((address_space(3))) unsigned int lds_u32;

__global__ __launch_bounds__(256, 4) void parts_linear_relu(
    const float* __restrict__ x, const float* __restrict__ W,
    const float* __restrict__ bias, float* __restrict__ out)
{
  __shared__ float wbuf[KDIM * ODIM];       // 16 KiB, W[p] linear [k][o]

  const int tid  = threadIdx.x;
  const int wave = tid >> 6;
  const int lane = tid & 63;                // output channel o

  const int p  = blockIdx.x & 63;
  const int g  = blockIdx.x >> 6;
  const int b0 = g * ROWS_PER_BLOCK;

  // --- stage W[p] (16 KiB) linearly into LDS: 4 passes x 256 thr x 16B ---
  {
    const float* Wp = W + p * (KDIM * ODIM);
    char* dst0 = (char*)wbuf + tid * 16;
#pragma unroll
    for (int i = 0; i < 4; ++i) {
      __builtin_amdgcn_global_load_lds(
          (gl_u32*)(Wp + i * 1024 + tid * 4),
          (lds_u32*)(dst0 + i * 4096), 16, 0, 0);
    }
  }
  const float bv = bias[p * ODIM + lane];
  __syncthreads();   // vmcnt(0) drain at barrier -> wbuf ready for all

  for (int c = 0; c < NSLABS; ++c) {
    const int row0 = b0 + c * 64 + wave * SLABROWS;
    const float* xr0 = x + (size_t)row0 * PK + p * KDIM;

    float acc[SLABROWS];
#pragma unroll
    for (int r = 0; r < SLABROWS; ++r) acc[r] = 0.f;

#pragma unroll 1
    for (int k4 = 0; k4 < KDIM / 4; ++k4) {
      // W quad from LDS: stride-64-dword -> bank lane%32, 2-way = free
      const float w0 = wbuf[(4 * k4 + 0) * ODIM + lane];
      const float w1 = wbuf[(4 * k4 + 1) * ODIM + lane];
      const float w2 = wbuf[(4 * k4 + 2) * ODIM + lane];
      const float w3 = wbuf[(4 * k4 + 3) * ODIM + lane];

      // two groups of 8 rows: <=8 quads (32 VGPR) in flight per group,
      // scheduler may still overlap group B loads with group A FMAs
#pragma unroll
      for (int h = 0; h < 2; ++h) {
        float4 xq[8];
#pragma unroll
        for (int r = 0; r < 8; ++r)
          xq[r] = *reinterpret_cast<const float4*>(
                      xr0 + (size_t)(h * 8 + r) * PK + 4 * k4);
#pragma unroll
        for (int r = 0; r < 8; ++r) {
          float a = acc[h * 8 + r];
          a = fmaf(xq[r].x, w0, a);
          a = fmaf(xq[r].y, w1, a);
          a = fmaf(xq[r].z, w2, a);
          a = fmaf(xq[r].w, w3, a);
          acc[h * 8 + r] = a;
        }
      }
    }

    float* o0 = out + (size_t)row0 * PK + p * ODIM + lane;
#pragma unroll
    for (int r = 0; r < SLABROWS; ++r) {
      o0[(size_t)r * PK] = fmaxf(acc[r] + bv, 0.0f);   // 256B coalesced
    }
  }
}

extern "C" void kernel_launch(void* const* d_in, const int* in_sizes, int n_in,
                              void* d_out, int out_size, void* d_ws, size_t ws_size,
                              hipStream_t stream) {
  const float* x    = (const float*)d_in[0];
  const float* W    = (const float*)d_in[1];
  const float* bias = (const float*)d_in[2];
  float* out        = (float*)d_out;

  // grid: 64 parts x 64 row-groups = 4096 blocks of 256 threads
  dim3 grid(64 * NBLOCKGROUPS);
  parts_linear_relu<<<grid, 256, 0, stream>>>(x, W, bias, out);
}

// Round 9
// 454.097 us; speedup vs baseline: 1.9107x; 1.9107x over previous
//
#include <hip/hip_runtime.h>

// Block-diagonal linear + bias + ReLU on MI355X (gfx950).
// out[b,p,o] = relu(sum_k x[b,p,k] * W[p,k,o] + bias[p,o])
// B=16384, P=64, K=64, O=64, fp32 in/out.
//
// R5 (x-from-LDS): LDS-issue-bound, 222us. R7 (x-from-VMEM-broadcast):
// latency-bound w/ compiler-throttled MLP, 578us. Root cause both times:
// with lane=o, per-lane x reuse is 1 -> 4 FMA per 16B feed on SOME pipe.
// fp32 VALU needs 1 B/FLOP; LDS gives 0.5. Structural fix: MFMA.
//
// R8: bf16-split MFMA (x=xh+xl, W=wh+wl; D = xh*wh + xl*wh + xh*wl at
// 16x16x32; error ~1e-4 << tol). x is staged PRE-CONVERTED into MFMA
// A-fragment layout in LDS (per-lane 16B slots) so compute reads are
// linear conflict-free ds_read_b128 at lane*16. Staging is reg-mediated
// (coalesced float4 global -> cvt -> ds_write), double-buffered, loads
// for chunk c+1 issued before compute of chunk c (T14 split).
// W[p] staged once via global_load_lds; B-fragments (hi+lo) built once
// per block into 64 VGPRs and reused over all 256 rows.
// (R8 bench was an infra GPUAcquisitionTimeout — identical kernel
// resubmitted for measurement.)
//
// Fragment layouts (gfx950 16x16x32 bf16):
//   A: lane l holds A[m = l&15][k = 8*(l>>4) + j], j=0..7  (bf16x8)
//   B: lane l holds B[k = 8*(l>>4) + j][n = l&15]
//   D: lane l, reg i = D[(l>>4)*4 + i][l&15]   (guide-verified m89)

#define PK 4096   // row stride of x/out in floats (P*K = P*O)

using f32x4  = __attribute__((ext_vector_type(4))) float;
using bf16x8 = __attribute__((ext_vector_type(8))) short;
using u16x4  = __attribute__((ext_vector_type(4))) unsigned short;

typedef __attribute__((address_space(1))) const unsigned int gl_u32;
typedef __attribute__((address_space(3))) unsigned int lds_u32;

__device__ __forceinline__ unsigned short f2bf(float v) {
  unsigned u = __float_as_uint(v);
  u += 0x7fffu + ((u >> 16) & 1u);          // round-to-nearest-even
  return (unsigned short)(u >> 16);
}
__device__ __forceinline__ float bf2f(unsigned short us) {
  return __uint_as_float((unsigned)us << 16);
}

__global__ __launch_bounds__(256, 3) void parts_mfma_relu(
    const float* __restrict__ x, const float* __restrict__ W,
    const float* __restrict__ bias, float* __restrict__ out)
{
  // wbuf: W[p] fp32 linear [k][o] (16KB). afrag: A-fragments, 2 dbuf x
  // {hi,lo} x (4 mtiles x 2 h x 64 lanes) slots x 8 ushort = 32KB.
  __shared__ float wbuf[64 * 64];
  __shared__ unsigned short afrag[2][2][4096];

  const int tid  = threadIdx.x;
  const int wave = tid >> 6;      // = m-tile within chunk
  const int lane = tid & 63;

  const int p  = blockIdx.x & 63;
  const int g  = blockIdx.x >> 6;
  const int b0 = g * 256;         // 256 rows per block

  // ---- stage W[p] (16KB) into LDS, linear, async DMA ----
  {
    const float* Wp = W + p * 4096;
    char* dst0 = (char*)wbuf + tid * 16;
#pragma unroll
    for (int i = 0; i < 4; ++i) {
      __builtin_amdgcn_global_load_lds(
          (gl_u32*)(Wp + i * 1024 + tid * 4),
          (lds_u32*)(dst0 + i * 4096), 16, 0, 0);
    }
  }

  // ---- issue chunk-0 x loads (coalesced float4; row=(tid>>4)+16i) ----
  float4 x0, x1, x2, x3;
  auto load_chunk = [&](int c) {
    const float* src = x + (size_t)(b0 + c * 64 + (tid >> 4)) * PK
                         + p * 64 + 4 * (tid & 15);
    x0 = *(const float4*)(src);
    x1 = *(const float4*)(src + (size_t)16 * PK);
    x2 = *(const float4*)(src + (size_t)32 * PK);
    x3 = *(const float4*)(src + (size_t)48 * PK);
  };
  load_chunk(0);

  // bias values for this lane's 4 n-tiles
  float bv[4];
#pragma unroll
  for (int t = 0; t < 4; ++t) bv[t] = bias[p * 64 + 16 * t + (lane & 15)];

  __syncthreads();   // barrier drains vmcnt -> wbuf (and x0..x3) ready

  // ---- build B-fragments (hi+lo) in registers, once per block ----
  bf16x8 Bh[4][2], Bl[4][2];
#pragma unroll
  for (int t = 0; t < 4; ++t)
#pragma unroll
    for (int h = 0; h < 2; ++h) {
      bf16x8 vh, vl;
#pragma unroll
      for (int j = 0; j < 8; ++j) {
        const float v = wbuf[(32 * h + 8 * (lane >> 4) + j) * 64
                             + 16 * t + (lane & 15)];
        const unsigned short hu = f2bf(v);
        vh[j] = (short)hu;
        vl[j] = (short)f2bf(v - bf2f(hu));
      }
      Bh[t][h] = vh;
      Bl[t][h] = vl;
    }

  // ---- convert one staged unit (float4) into A-frag slots ----
  auto cvt_store_one = [&](int buf, int i, const float4& v) {
    const int r  = (tid >> 4) + 16 * i;   // row in chunk [0,64)
    const int q  = tid & 15;              // 4-float k-chunk [0,16)
    const int mt = r >> 4, m = r & 15;
    const int h = q >> 3, gg = (q >> 1) & 3, j4 = q & 1;
    const int ui = ((mt * 2 + h) * 64 + (m + 16 * gg)) * 8 + j4 * 4;
    const float f0 = v.x, f1 = v.y, f2 = v.z, f3 = v.w;
    u16x4 hi, lo;
    unsigned short hu;
    hu = f2bf(f0); hi[0] = hu; lo[0] = f2bf(f0 - bf2f(hu));
    hu = f2bf(f1); hi[1] = hu; lo[1] = f2bf(f1 - bf2f(hu));
    hu = f2bf(f2); hi[2] = hu; lo[2] = f2bf(f2 - bf2f(hu));
    hu = f2bf(f3); hi[3] = hu; lo[3] = f2bf(f3 - bf2f(hu));
    *(u16x4*)&afrag[buf][0][ui] = hi;
    *(u16x4*)&afrag[buf][1][ui] = lo;
  };
  auto cvt_store = [&](int buf) {
    cvt_store_one(buf, 0, x0);
    cvt_store_one(buf, 1, x1);
    cvt_store_one(buf, 2, x2);
    cvt_store_one(buf, 3, x3);
  };

  // ---- compute one 64-row chunk: wave w does m-tile w ----
  auto compute_chunk = [&](int buf, int c) {
    f32x4 acc[4];
#pragma unroll
    for (int t = 0; t < 4; ++t) acc[t] = (f32x4){0.f, 0.f, 0.f, 0.f};
#pragma unroll
    for (int h = 0; h < 2; ++h) {
      const int ai = ((wave * 2 + h) * 64 + lane) * 8;
      const bf16x8 ah = *(const bf16x8*)&afrag[buf][0][ai];
      const bf16x8 al = *(const bf16x8*)&afrag[buf][1][ai];
#pragma unroll
      for (int t = 0; t < 4; ++t) {
        acc[t] = __builtin_amdgcn_mfma_f32_16x16x32_bf16(ah, Bh[t][h], acc[t], 0, 0, 0);
        acc[t] = __builtin_amdgcn_mfma_f32_16x16x32_bf16(al, Bh[t][h], acc[t], 0, 0, 0);
        acc[t] = __builtin_amdgcn_mfma_f32_16x16x32_bf16(ah, Bl[t][h], acc[t], 0, 0, 0);
      }
    }
    const int rbase = b0 + c * 64 + wave * 16 + (lane >> 4) * 4;
    const int obase = p * 64 + (lane & 15);
#pragma unroll
    for (int t = 0; t < 4; ++t)
#pragma unroll
      for (int i = 0; i < 4; ++i) {
        const float vv = acc[t][i] + bv[t];
        out[(size_t)(rbase + i) * PK + obase + 16 * t] = fmaxf(vv, 0.f);
      }
  };

  // ---- pipeline: convert c, prefetch c+1, barrier, compute c ----
  cvt_store(0);        // chunk0 -> buf0
  load_chunk(1);
  __syncthreads();     // buf0 frags visible

  compute_chunk(0, 0);
  cvt_store(1);        // chunk1 -> buf1 (x1 regs; waitcnt auto)
  load_chunk(2);
  __syncthreads();

  compute_chunk(1, 1);
  cvt_store(0);        // chunk2 -> buf0 (all waves done reading buf0)
  load_chunk(3);
  __syncthreads();

  compute_chunk(0, 2);
  cvt_store(1);        // chunk3 -> buf1
  __syncthreads();

  compute_chunk(1, 3);
}

extern "C" void kernel_launch(void* const* d_in, const int* in_sizes, int n_in,
                              void* d_out, int out_size, void* d_ws, size_t ws_size,
                              hipStream_t stream) {
  const float* x    = (const float*)d_in[0];
  const float* W    = (const float*)d_in[1];
  const float* bias = (const float*)d_in[2];
  float* out        = (float*)d_out;

  // grid: 64 parts x 64 row-groups (256 rows each) = 4096 blocks
  dim3 grid(4096);
  parts_mfma_relu<<<grid, 256, 0, stream>>>(x, W, bias, out);
}